// Round 10
// baseline (378.640 us; speedup 1.0000x reference)
//
#include <hip/hip_runtime.h>
#include <hip/hip_bf16.h>
#include <math.h>

#define B_    16
#define L_    2048
#define H_    512
#define NT_   8
#define OUT_  1032
#define HEAD_ 256
#define CH_   16
#define CL_   (L_/CH_)   // 128
#define NWS_  1152       // AT row stride in shorts (z|h then hbi in-place)
#define KP2_  1088       // head GEMM K (17 x 64)

typedef short bf16x8 __attribute__((ext_vector_type(8)));
typedef float f32x4  __attribute__((ext_vector_type(4)));

__device__ __forceinline__ float b2f(unsigned short u) {
    union { unsigned int u32; float f; } v; v.u32 = ((unsigned int)u) << 16; return v.f;
}
__device__ __forceinline__ unsigned short f2b(float f) {
    __hip_bfloat16 h = __float2bfloat16(f);
    return *reinterpret_cast<unsigned short*>(&h);
}
__device__ __forceinline__ float sigmoid_f(float x) {
    return 1.f / (1.f + exp2f(-1.44269504f * x));
}
__device__ __forceinline__ float tanh_f(float x) {
    float e = exp2f(2.88539008f * x);
    return 1.f - 2.f / (e + 1.f);
}
__device__ __forceinline__ float gelu_f(float g) {
    float u  = 0.70710678118654752f * g;
    float ax = fabsf(u);
    float t  = 1.f / (1.f + 0.3275911f * ax);
    float poly = ((((1.061405429f*t - 1.453152027f)*t + 1.421413741f)*t
                   - 0.284496736f)*t + 0.254829592f)*t;
    float e  = exp2f(-1.44269504f * ax * ax);
    float er = 1.f - poly * e;
    er = (u < 0.f) ? -er : er;
    return 0.5f * g * (1.f + er);
}

// ---------------------------------------------------------------------------
// kT: transpose + f32->bf16. in f32 [R][C] -> out bf16 [C][RP], zero r>=R.
// ---------------------------------------------------------------------------
__global__ __launch_bounds__(256) void kT(const float* __restrict__ in,
                                          unsigned short* __restrict__ out,
                                          int R, int C, int RP)
{
    __shared__ float tile[32][33];
    int c0 = blockIdx.x * 32, r0 = blockIdx.y * 32;
    int tx = threadIdx.x & 31, ty = threadIdx.x >> 5;
    #pragma unroll
    for (int j = 0; j < 32; j += 8) {
        int r = r0 + ty + j, c = c0 + tx;
        tile[ty + j][tx] = (r < R && c < C) ? in[(size_t)r*C + c] : 0.f;
    }
    __syncthreads();
    #pragma unroll
    for (int j = 0; j < 32; j += 8) {
        int c = c0 + ty + j, r = r0 + tx;
        if (c < C && r < RP) out[(size_t)c*RP + r] = f2b(tile[tx][ty + j]);
    }
}

// ---------------------------------------------------------------------------
// kP: pack Wg1 (f32 [OUT_][256]) into MFMA B-fragment chunks, 34 K-blocks:
// P[kb*1024 + c*4 + kg] = bf16 Wg1[kb*32+kg*8 .. +8][c]  (zero for k>=OUT_)
// ---------------------------------------------------------------------------
__global__ __launch_bounds__(256) void kP(const float* __restrict__ Wg1,
                                          uint4* __restrict__ P)
{
    int idx = blockIdx.x*256 + threadIdx.x;
    if (idx >= 34*1024) return;
    int kb = idx >> 10;
    int rem = idx & 1023;
    int c  = rem >> 2;
    int kg = rem & 3;
    int k0 = kb*32 + kg*8;
    unsigned short o[8];
    #pragma unroll
    for (int j = 0; j < 8; j++) {
        int k = k0 + j;
        o[j] = (k < OUT_) ? f2b(Wg1[(size_t)k*HEAD_ + c]) : (unsigned short)0;
    }
    P[idx] = *(const uint4*)o;
}

// ---------------------------------------------------------------------------
// K1 (per-dir): t_enc MLP + inp = xc @ Wp + bp. wave-per-row.
// ---------------------------------------------------------------------------
__global__ __launch_bounds__(256) void k1_tenc_inp(
    const float* __restrict__ x, const float* __restrict__ t,
    const float* __restrict__ Wt1, const float* __restrict__ bt1,
    const float* __restrict__ Wt2, const float* __restrict__ bt2,
    const float* __restrict__ Wp, const float* __restrict__ bp,
    float* __restrict__ t_enc,
    unsigned short* __restrict__ inp)
{
    int wv = threadIdx.x >> 6, lane = threadIdx.x & 63;
    size_t row = (size_t)blockIdx.x*4 + wv;
    float tv = t[row];
    float r1[NT_], te[NT_];
    #pragma unroll
    for (int k = 0; k < NT_; k++) r1[k] = fmaxf(tv*Wt1[k] + bt1[k], 0.f);
    #pragma unroll
    for (int j = 0; j < NT_; j++) {
        float a = bt2[j];
        #pragma unroll
        for (int k = 0; k < NT_; k++) a = fmaf(r1[k], Wt2[k*NT_+j], a);
        te[j] = a;
    }
    if (lane < NT_) t_enc[row*NT_ + lane] = te[lane];
    float x0 = x[row*2+0], x1 = x[row*2+1];
    int c0 = lane*8;
    float af[8];
    #pragma unroll
    for (int j = 0; j < 8; j++) {
        int c = c0 + j;
        af[j] = fmaf(x0, Wp[c], fmaf(x1, Wp[H_+c], bp[c]));
    }
    #pragma unroll
    for (int k = 0; k < NT_; k++) {
        #pragma unroll
        for (int j = 0; j < 8; j++)
            af[j] = fmaf(te[k], Wp[(2+k)*H_+c0+j], af[j]);
    }
    unsigned short of[8];
    #pragma unroll
    for (int j = 0; j < 8; j++) of[j] = f2b(af[j]);
    *(uint4*)&inp[row*H_ + c0] = *(const uint4*)of;
}

// ---------------------------------------------------------------------------
// K3g: PURE GEMM. AT[row][0..511] = inp@Wz (raw), AT[row][512..1023] = inp@Wh.
// 128x128 tile, BK=32, 80B-pad LDS, register prefetch, XCD remap.
// ---------------------------------------------------------------------------
__global__ __launch_bounds__(256) void k3g(
    const unsigned short* __restrict__ inp,   // [M][512] bf16
    const unsigned short* __restrict__ WT,    // [1024][512] bf16 (Wz rows, Wh rows)
    unsigned short* __restrict__ zt_out,      // [M][NWS_] bf16
    int nwg)
{
    __shared__ __align__(16) unsigned short As[128*40];
    __shared__ __align__(16) unsigned short Bs[128*40];
    int tid = threadIdx.x;
    int lane = tid & 63, w = tid >> 6;
    int wm = w >> 1, wn = w & 1;
    int kg = lane >> 4, lr = lane & 15;

    int bid = blockIdx.x;
    int cpx = nwg >> 3;
    int tile = (bid & 7) * cpx + (bid >> 3);
    int row0 = (tile >> 3) * 128;
    int n0   = (tile & 7) * 128;

    f32x4 acc[4][4];
    #pragma unroll
    for (int m = 0; m < 4; m++)
        #pragma unroll
        for (int n = 0; n < 4; n++) acc[m][n] = (f32x4){0.f,0.f,0.f,0.f};

    int ar = tid >> 1, aseg = tid & 1;

    uint4 va0, va1, vb0, vb1;
    {
        const uint4* ga = (const uint4*)&inp[(size_t)(row0+ar)*H_ + aseg*16];
        va0 = ga[0]; va1 = ga[1];
        const uint4* gb = (const uint4*)&WT[(size_t)(n0+ar)*H_ + aseg*16];
        vb0 = gb[0]; vb1 = gb[1];
    }

    for (int k0 = 0; k0 < H_; k0 += 32) {
        __syncthreads();
        *(uint4*)&As[ar*40 + aseg*16]     = va0;
        *(uint4*)&As[ar*40 + aseg*16 + 8] = va1;
        *(uint4*)&Bs[ar*40 + aseg*16]     = vb0;
        *(uint4*)&Bs[ar*40 + aseg*16 + 8] = vb1;
        __syncthreads();
        if (k0 + 32 < H_) {
            const uint4* ga = (const uint4*)&inp[(size_t)(row0+ar)*H_ + k0+32 + aseg*16];
            va0 = ga[0]; va1 = ga[1];
            const uint4* gb = (const uint4*)&WT[(size_t)(n0+ar)*H_ + k0+32 + aseg*16];
            vb0 = gb[0]; vb1 = gb[1];
        }
        bf16x8 af[4], bf[4];
        #pragma unroll
        for (int m = 0; m < 4; m++)
            af[m] = *(const bf16x8*)&As[(wm*64 + m*16 + lr)*40 + kg*8];
        #pragma unroll
        for (int n = 0; n < 4; n++)
            bf[n] = *(const bf16x8*)&Bs[(wn*64 + n*16 + lr)*40 + kg*8];
        #pragma unroll
        for (int m = 0; m < 4; m++)
            #pragma unroll
            for (int n = 0; n < 4; n++)
                acc[m][n] = __builtin_amdgcn_mfma_f32_16x16x32_bf16(af[m], bf[n], acc[m][n], 0, 0, 0);
    }

    #pragma unroll
    for (int m = 0; m < 4; m++)
        #pragma unroll
        for (int n = 0; n < 4; n++) {
            int colg = n0 + wn*64 + n*16 + lr;
            #pragma unroll
            for (int r = 0; r < 4; r++) {
                int rowg = row0 + wm*64 + m*16 + kg*4 + r;
                zt_out[(size_t)rowg*NWS_ + colg] = f2b(acc[m][n][r]);
            }
        }
}

// ---------------------------------------------------------------------------
// K4a: bias + activations + chunked scan pass A, in place on AT rows.
// ---------------------------------------------------------------------------
__global__ __launch_bounds__(256) void k4a(
    unsigned short* __restrict__ ATF, unsigned short* __restrict__ ATB,
    const float* __restrict__ bzf, const float* __restrict__ bhf,
    const float* __restrict__ bzb, const float* __restrict__ bhb,
    float* __restrict__ Scar, float* __restrict__ Pcar, int nb)
{
    int g = blockIdx.x*256 + threadIdx.x;
    int col   = g & (H_-1);
    int chunk = (g >> 9) & (CH_-1);
    int rest  = g >> 13;
    int bb    = rest % nb;
    int dir   = rest / nb;
    unsigned short* AT = dir ? ATB : ATF;
    float bzv = (dir ? bzb : bzf)[col];
    float bhv = (dir ? bhb : bhf)[col];
    size_t base = (size_t)bb * L_ * NWS_ + col;
    float h = 0.f, pp = 1.f;
    if (dir == 0) {
        int lo = chunk * CL_;
        for (int p = 0; p < CL_; p += 8) {
            unsigned short zv[8], hv[8];
            #pragma unroll
            for (int j = 0; j < 8; j++) {
                size_t idx = base + (size_t)(lo+p+j)*NWS_;
                zv[j] = AT[idx]; hv[j] = AT[idx + H_];
            }
            #pragma unroll
            for (int j = 0; j < 8; j++) {
                size_t idx = base + (size_t)(lo+p+j)*NWS_;
                float zg = sigmoid_f(b2f(zv[j]) + bzv);
                float a  = 1.f - zg;
                float bg = zg * tanh_f(b2f(hv[j]) + bhv);
                AT[idx]      = f2b(h);
                AT[idx + H_] = f2b(pp);
                h = fmaf(a, h, bg);
                pp *= a;
            }
        }
    } else {
        int hi = chunk * CL_ + CL_ - 1;
        for (int p = 0; p < CL_; p += 8) {
            unsigned short zv[8], hv[8];
            #pragma unroll
            for (int j = 0; j < 8; j++) {
                size_t idx = base + (size_t)(hi-p-j)*NWS_;
                zv[j] = AT[idx]; hv[j] = AT[idx + H_];
            }
            #pragma unroll
            for (int j = 0; j < 8; j++) {
                size_t idx = base + (size_t)(hi-p-j)*NWS_;
                float zg = sigmoid_f(b2f(zv[j]) + bzv);
                float a  = 1.f - zg;
                float bg = zg * tanh_f(b2f(hv[j]) + bhv);
                AT[idx]      = f2b(h);
                AT[idx + H_] = f2b(pp);
                h = fmaf(a, h, bg);
                pp *= a;
            }
        }
    }
    int ci = ((dir*nb + bb)*CH_ + chunk)*H_ + col;
    Scar[ci] = h; Pcar[ci] = pp;
}

// K4b: chain carries across chunks.
__global__ __launch_bounds__(256) void k4b(
    const float* __restrict__ Scar, const float* __restrict__ Pcar,
    float* __restrict__ Hstart, int nb)
{
    int g = blockIdx.x*256 + threadIdx.x;
    int col  = g & (H_-1);
    int rest = g >> 9;
    int bb   = rest % nb;
    int dir  = rest / nb;
    int baseci = (dir*nb + bb)*CH_;
    float h = 0.f;
    if (dir == 0) {
        for (int c = 0; c < CH_; c++) {
            int ci = (baseci + c)*H_ + col;
            Hstart[ci] = h;
            h = Scar[ci] + Pcar[ci]*h;
        }
    } else {
        for (int c = CH_-1; c >= 0; c--) {
            int ci = (baseci + c)*H_ + col;
            Hstart[ci] = h;
            h = Scar[ci] + Pcar[ci]*h;
        }
    }
}

// ---------------------------------------------------------------------------
// K5a: streaming LN. h = S + PP*h0 (both dirs), LN(1032), affine + ts.
// Writes hbi bf16 IN-PLACE into the ATF row slot: [0..511]=fwd, [512..1023]=
// bwd, [1024..1031]=tenc-part, [1032..1087]=0. Wave-per-row (safe in-place).
// ---------------------------------------------------------------------------
__global__ __launch_bounds__(256) void k5a_ln(
    unsigned short* __restrict__ ATF, const unsigned short* __restrict__ ATB,
    const float* __restrict__ Hstart, const float* __restrict__ tenc,
    const float* __restrict__ ln_g, const float* __restrict__ ln_b,
    const float* __restrict__ tsp, int nb)
{
    int wv = threadIdx.x >> 6, lane = threadIdx.x & 63;
    size_t row = (size_t)blockIdx.x*4 + wv;
    int bb    = (int)(row >> 11);
    int chunk = ((int)row & (L_-1)) >> 7;
    int cif = (bb*CH_ + chunk)*H_;
    int cib = ((nb + bb)*CH_ + chunk)*H_;
    int c0 = lane*8;
    float ts = tsp[0];

    size_t rb = row * NWS_;
    uint4 SF = *(const uint4*)&ATF[rb + c0];
    uint4 PF = *(const uint4*)&ATF[rb + H_ + c0];
    uint4 SB = *(const uint4*)&ATB[rb + c0];
    uint4 PB = *(const uint4*)&ATB[rb + H_ + c0];
    float4 hfa = *(const float4*)&Hstart[cif + c0];
    float4 hfb = *(const float4*)&Hstart[cif + c0 + 4];
    float4 hba = *(const float4*)&Hstart[cib + c0];
    float4 hbb = *(const float4*)&Hstart[cib + c0 + 4];
    float h0f[8] = {hfa.x,hfa.y,hfa.z,hfa.w,hfb.x,hfb.y,hfb.z,hfb.w};
    float h0b[8] = {hba.x,hba.y,hba.z,hba.w,hbb.x,hbb.y,hbb.z,hbb.w};
    const unsigned short* sf = (const unsigned short*)&SF;
    const unsigned short* pf = (const unsigned short*)&PF;
    const unsigned short* sb = (const unsigned short*)&SB;
    const unsigned short* pb = (const unsigned short*)&PB;

    float fv[8], bv[8];
    float S = 0.f, Q = 0.f;
    #pragma unroll
    for (int j = 0; j < 8; j++) {
        fv[j] = fmaf(b2f(pf[j]), h0f[j], b2f(sf[j]));
        S += fv[j]; Q += fv[j]*fv[j];
        bv[j] = fmaf(b2f(pb[j]), h0b[j], b2f(sb[j]));
        S += bv[j]; Q += bv[j]*bv[j];
    }
    float tv = 0.f;
    if (lane < NT_) { tv = tenc[row*NT_ + lane]; S += tv; Q += tv*tv; }
    #pragma unroll
    for (int off = 32; off > 0; off >>= 1) {
        S += __shfl_xor(S, off, 64);
        Q += __shfl_xor(Q, off, 64);
    }
    float mu = S * (1.f/1032.f);
    float rs = rsqrtf(Q * (1.f/1032.f) - mu*mu + 1e-5f);

    unsigned short o[8];
    #pragma unroll
    for (int j = 0; j < 8; j++)
        o[j] = f2b((fv[j]-mu)*rs*ln_g[c0+j] + ln_b[c0+j]);
    *(uint4*)&ATF[rb + c0] = *(const uint4*)o;
    #pragma unroll
    for (int j = 0; j < 8; j++)
        o[j] = f2b((bv[j]-mu)*rs*ln_g[H_+c0+j] + ln_b[H_+c0+j]);
    *(uint4*)&ATF[rb + H_ + c0] = *(const uint4*)o;
    if (lane < NT_) {
        int c = 2*H_ + lane;
        ATF[rb + 1024 + lane] = f2b(((tv-mu)*rs*ln_g[c] + ln_b[c]) * ts);
    } else {
        ATF[rb + 1024 + lane] = 0;   // lanes 8..63 zero cols 1032..1087
    }
}

// ---------------------------------------------------------------------------
// K5b: head GEMM. M-tile 64 x N 256, K=1088 in 17 steps of 64. A from hbi
// (=ATF rows), B from packed P staged into LDS in fragment order (read is
// linear per lane -> conflict-free). Register prefetch of next step. Fused
// gelu*Wg2 + row-reduce epilogue. 4 waves (2m x 2n), wave tile 32x128.
// ---------------------------------------------------------------------------
__global__ __launch_bounds__(256, 2) void k5b_head(
    const unsigned short* __restrict__ hbi,   // ATF, stride NWS_
    const uint4* __restrict__ P,              // [34*1024] packed fragments
    const float* __restrict__ bg1, const float* __restrict__ Wg2,
    const float* __restrict__ bg2,
    float* __restrict__ out, int nwg)
{
    __shared__ __align__(16) unsigned short As[64*68];  // 8.5 KB
    __shared__ __align__(16) uint4 Bs[2048];            // 32 KB
    __shared__ float red[2][64];
    int tid = threadIdx.x, lane = tid & 63, w = tid >> 6;
    int wm = w >> 1, wn = w & 1;
    int lr = lane & 15, kg = lane >> 4;

    int bid = blockIdx.x;
    int cpx = nwg >> 3;
    int tile = (bid & 7) * cpx + (bid >> 3);
    int row0 = tile * 64;

    f32x4 acc[2][8];
    #pragma unroll
    for (int m = 0; m < 2; m++)
        #pragma unroll
        for (int n = 0; n < 8; n++) acc[m][n] = (f32x4){0.f,0.f,0.f,0.f};

    int arow = tid & 63, ac8 = tid >> 6;   // A: this thread stages chunks ac8, ac8+4
    const unsigned short* asrc = &hbi[(size_t)(row0 + arow)*NWS_];

    uint4 va0, va1, vb[8];
    // prologue: prefetch step 0
    va0 = *(const uint4*)&asrc[ac8*8];
    va1 = *(const uint4*)&asrc[(ac8+4)*8];
    #pragma unroll
    for (int j = 0; j < 8; j++) vb[j] = P[tid*8 + j];

    for (int step = 0; step < 17; step++) {
        __syncthreads();
        *(uint4*)&As[arow*68 + ac8*8]     = va0;
        *(uint4*)&As[arow*68 + (ac8+4)*8] = va1;
        #pragma unroll
        for (int j = 0; j < 8; j++) {
            int i = tid*8 + j;
            int kbl = (i >> 10) & 1;
            int c   = (i & 1023) >> 2;
            int kgw = i & 3;
            Bs[kbl*1024 + (c>>4)*64 + kgw*16 + (c&15)] = vb[j];
        }
        __syncthreads();
        if (step < 16) {
            int k0 = (step+1)*64;
            va0 = *(const uint4*)&asrc[k0 + ac8*8];
            va1 = *(const uint4*)&asrc[k0 + (ac8+4)*8];
            const uint4* ps = P + (step+1)*2048 + tid*8;
            #pragma unroll
            for (int j = 0; j < 8; j++) vb[j] = ps[j];
        }
        #pragma unroll
        for (int kk = 0; kk < 2; kk++) {
            bf16x8 af0 = *(const bf16x8*)&As[(wm*32 + lr)*68      + (kk*4+kg)*8];
            bf16x8 af1 = *(const bf16x8*)&As[(wm*32 + 16 + lr)*68 + (kk*4+kg)*8];
            #pragma unroll
            for (int n = 0; n < 8; n++) {
                bf16x8 bf = *(const bf16x8*)&Bs[kk*1024 + (wn*8+n)*64 + lane];
                acc[0][n] = __builtin_amdgcn_mfma_f32_16x16x32_bf16(af0, bf, acc[0][n], 0, 0, 0);
                acc[1][n] = __builtin_amdgcn_mfma_f32_16x16x32_bf16(af1, bf, acc[1][n], 0, 0, 0);
            }
        }
    }

    // epilogue: gelu + *Wg2, reduce over this wave's 128 cols
    float rsum[2][4] = {{0.f,0.f,0.f,0.f},{0.f,0.f,0.f,0.f}};
    #pragma unroll
    for (int n = 0; n < 8; n++) {
        int colg = wn*128 + n*16 + lr;
        float bgv = bg1[colg], w2v = Wg2[colg];
        #pragma unroll
        for (int m = 0; m < 2; m++)
            #pragma unroll
            for (int r = 0; r < 4; r++) {
                float gv = gelu_f(acc[m][n][r] + bgv);
                rsum[m][r] = fmaf(gv, w2v, rsum[m][r]);
            }
    }
    #pragma unroll
    for (int off = 1; off < 16; off <<= 1)
        #pragma unroll
        for (int m = 0; m < 2; m++)
            #pragma unroll
            for (int r = 0; r < 4; r++)
                rsum[m][r] += __shfl_xor(rsum[m][r], off, 64);
    if (lr == 0) {
        #pragma unroll
        for (int m = 0; m < 2; m++)
            #pragma unroll
            for (int r = 0; r < 4; r++)
                red[wn][wm*32 + m*16 + kg*4 + r] = rsum[m][r];
    }
    __syncthreads();
    if (tid < 64)
        out[row0 + tid] = red[0][tid] + red[1][tid] + bg2[0];
}

// ---------------------------------------------------------------------------
extern "C" void kernel_launch(void* const* d_in, const int* in_sizes, int n_in,
                              void* d_out, int out_size, void* d_ws, size_t ws_size,
                              hipStream_t stream)
{
    const float* x    = (const float*)d_in[0];
    const float* t    = (const float*)d_in[1];
    const float* Wt1  = (const float*)d_in[2];
    const float* bt1  = (const float*)d_in[3];
    const float* Wt2  = (const float*)d_in[4];
    const float* bt2  = (const float*)d_in[5];
    const float* Wpf  = (const float*)d_in[6];
    const float* bpf  = (const float*)d_in[7];
    const float* Wpb  = (const float*)d_in[8];
    const float* bpb  = (const float*)d_in[9];
    const float* Wzf  = (const float*)d_in[10];
    const float* bzf  = (const float*)d_in[11];
    const float* Whf  = (const float*)d_in[12];
    const float* bhf  = (const float*)d_in[13];
    const float* Wzb  = (const float*)d_in[14];
    const float* bzb  = (const float*)d_in[15];
    const float* Whb  = (const float*)d_in[16];
    const float* bhb  = (const float*)d_in[17];
    const float* ln_g = (const float*)d_in[18];
    const float* ln_b = (const float*)d_in[19];
    const float* tsc  = (const float*)d_in[20];
    const float* Wg1  = (const float*)d_in[21];
    const float* bg1  = (const float*)d_in[22];
    const float* Wg2  = (const float*)d_in[23];
    const float* bg2  = (const float*)d_in[24];
    float* out = (float*)d_out;

    char* p = (char*)d_ws;
    auto carve = [&](size_t bytes) -> char* {
        char* q = p; p += (bytes + 255) & ~(size_t)255; return q;
    };

    unsigned short* WTf = (unsigned short*)carve((size_t)2*H_*H_*2);
    unsigned short* WTb = (unsigned short*)carve((size_t)2*H_*H_*2);
    uint4*          Pg  = (uint4*)carve((size_t)34*1024*16);

    const size_t perBatch = (size_t)L_*H_*2            // inp
                          + (size_t)L_*NWS_*2*2        // ATF + ATB
                          + (size_t)L_*NT_*4           // tenc
                          + (size_t)CH_*H_*4*3*2;      // carries
    size_t fixedUsed = (size_t)(p - (char*)d_ws) + 64*1024;
    int NB = B_;
    while (NB > 1 && fixedUsed + (size_t)NB*perBatch > ws_size) NB >>= 1;

    unsigned short* inp = (unsigned short*)carve((size_t)NB*L_*H_*2);
    unsigned short* ATF = (unsigned short*)carve((size_t)NB*L_*NWS_*2);
    unsigned short* ATB = (unsigned short*)carve((size_t)NB*L_*NWS_*2);
    float* tenc   = (float*)carve((size_t)NB*L_*NT_*4);
    float* Scar   = (float*)carve((size_t)2*NB*CH_*H_*4);
    float* Pcar   = (float*)carve((size_t)2*NB*CH_*H_*4);
    float* Hstart = (float*)carve((size_t)2*NB*CH_*H_*4);

    {
        dim3 g(H_/32, H_/32);
        kT<<<g, 256, 0, stream>>>(Wzf, WTf,         H_, H_, H_);
        kT<<<g, 256, 0, stream>>>(Whf, WTf + H_*H_, H_, H_, H_);
        kT<<<g, 256, 0, stream>>>(Wzb, WTb,         H_, H_, H_);
        kT<<<g, 256, 0, stream>>>(Whb, WTb + H_*H_, H_, H_, H_);
        kP<<<136, 256, 0, stream>>>(Wg1, Pg);
    }

    for (int b0 = 0; b0 < B_; b0 += NB) {
        int rows = NB * L_;
        int nwg3 = (rows/128) * 8;

        k1_tenc_inp<<<rows/4, 256, 0, stream>>>(
            x + (size_t)b0*L_*2, t + (size_t)b0*L_,
            Wt1, bt1, Wt2, bt2, Wpf, bpf, tenc, inp);
        k3g<<<nwg3, 256, 0, stream>>>(inp, WTf, ATF, nwg3);

        k1_tenc_inp<<<rows/4, 256, 0, stream>>>(
            x + (size_t)b0*L_*2, t + (size_t)b0*L_,
            Wt1, bt1, Wt2, bt2, Wpb, bpb, tenc, inp);
        k3g<<<nwg3, 256, 0, stream>>>(inp, WTb, ATB, nwg3);

        int scanThreads = 2*NB*H_*CH_;
        k4a<<<scanThreads/256, 256, 0, stream>>>(ATF, ATB, bzf, bhf, bzb, bhb,
                                                 Scar, Pcar, NB);
        k4b<<<(2*NB*H_)/256, 256, 0, stream>>>(Scar, Pcar, Hstart, NB);

        k5a_ln<<<rows/4, 256, 0, stream>>>(ATF, ATB, Hstart, tenc,
                                           ln_g, ln_b, tsc, NB);

        int nwg5 = rows/64;
        k5b_head<<<nwg5, 256, 0, stream>>>(ATF, Pg, bg1, Wg2, bg2,
                                           out + (size_t)b0*L_, nwg5);
    }
}